// Round 12
// baseline (159.780 us; speedup 1.0000x reference)
//
#include <hip/hip_runtime.h>
#include <hip/hip_cooperative_groups.h>

namespace cg = cooperative_groups;

// Problem dims (fixed by the reference)
#define LW   16      // chars per word (max)
#define GD   300     // glove dim
#define CEM  64      // char emb dim
#define OD   100     // out dim of conv/linear
#define NCH  128     // char vocab
#define NW   (32 * 512)   // 16384 words
#define NQ   (NW / 4)     // 4096 word-quads (4 words = 4 waves of one block)
#define GRID 1024

// d_ws layout (floats):
//   [0     .. 12800)  T[128][100]   T[ch][o] = sum_e ce[ch][e] * Wc[e][o]
//   [12800 .. 12900)  c[100]
//   [12900 .. 12928)  pad (junk-lane bias reads touch up to 12927)

// ---------------- single cooperative kernel ----------------
// Phase A: blocks 0..127 = precompute T (R5 body); blocks 128..1023 stream
//          glove quads (no dependency on T).  grid.sync().
// Phase B: all blocks grid-stride the char path (reads T).
__global__ __launch_bounds__(256, 4) void mono(
        const int*   __restrict__ word_tokens,
        const int*   __restrict__ char_ids,
        const int*   __restrict__ char_lens,
        const float* __restrict__ glove,
        const float* __restrict__ char_table,
        const float* __restrict__ conv_w,
        const float* __restrict__ conv_b,
        const float* __restrict__ lin_w,
        const float* __restrict__ lin_b,
        float* __restrict__ ws,
        float* __restrict__ out) {
    const int bid  = blockIdx.x;
    const int wave = threadIdx.x >> 6;
    const int lane = threadIdx.x & 63;

    // ---------------- phase A ----------------
    if (bid < NCH) {
        // R5 precompute_T body (threads 128..255 idle)
        __shared__ float ceS[CEM];
        __shared__ float U[OD];
        const int t  = threadIdx.x;
        const int ch = bid;

        if (t < CEM) ceS[t] = char_table[ch * CEM + t];
        __syncthreads();

        if (t < OD) {
            const float* cw = conv_w + t * CEM;
            float a0 = 0.f, a1 = 0.f, a2 = 0.f, a3 = 0.f;
            #pragma unroll
            for (int e = 0; e < CEM; e += 4) {
                a0 = fmaf(cw[e + 0], ceS[e + 0], a0);
                a1 = fmaf(cw[e + 1], ceS[e + 1], a1);
                a2 = fmaf(cw[e + 2], ceS[e + 2], a2);
                a3 = fmaf(cw[e + 3], ceS[e + 3], a3);
            }
            U[t] = (a0 + a1) + (a2 + a3);
        }
        __syncthreads();

        if (t < OD) {
            const float* lw = lin_w + t * OD;
            float a0 = 0.f, a1 = 0.f, a2 = 0.f, a3 = 0.f;
            #pragma unroll 5
            for (int j = 0; j < OD; j += 4) {
                a0 = fmaf(lw[j + 0], U[j + 0], a0);
                a1 = fmaf(lw[j + 1], U[j + 1], a1);
                a2 = fmaf(lw[j + 2], U[j + 2], a2);
                a3 = fmaf(lw[j + 3], U[j + 3], a3);
            }
            ws[ch * OD + t] = (a0 + a1) + (a2 + a3);

            if (ch == 0) {
                float b0 = lin_b[t], b1 = 0.f, b2 = 0.f, b3 = 0.f;
                #pragma unroll 5
                for (int j = 0; j < OD; j += 4) {
                    b0 = fmaf(lw[j + 0], conv_b[j + 0], b0);
                    b1 = fmaf(lw[j + 1], conv_b[j + 1], b1);
                    b2 = fmaf(lw[j + 2], conv_b[j + 2], b2);
                    b3 = fmaf(lw[j + 3], conv_b[j + 3], b3);
                }
                ws[NCH * OD + t] = (b0 + b1) + (b2 + b3);
            }
        }
    } else {
        // glove quads: blocks 128..1023 cover quads 0..4095 (4-5 each)
        #pragma unroll 1
        for (int q = bid - NCH; q < NQ; q += GRID - NCH) {
            const int word = q * 4 + wave;
            const int tok = word_tokens[word];          // wave-uniform
            const float4* g4 = (const float4*)(glove + (size_t)tok * GD);
            float4 g0 = g4[lane];
            float4 g1;
            const bool tail = lane < (GD / 4 - 64);     // lanes 0..10
            if (tail) g1 = g4[64 + lane];

            float4* d4 = (float4*)(out + (size_t)word * (GD + OD));
            d4[lane] = g0;
            if (tail) d4[64 + lane] = g1;
        }
    }

    cg::this_grid().sync();

    // ---------------- phase B: char path (R5 body), 4 quads/block ----------------
    #pragma unroll 1
    for (int q = bid; q < NQ; q += GRID) {
        const int word = q * 4 + wave;
        const int len = char_lens[word];                // wave-uniform, >= 1

        const int4* cid4 = (const int4*)(char_ids + (size_t)word * LW);
        const int4 i0 = cid4[0], i1 = cid4[1], i2 = cid4[2], i3 = cid4[3];

        const float cl = ws[NCH * OD + lane];                      // c[lane]
        const bool hi = lane < (OD - 64);                          // lanes 0..35
        const float chv = ws[NCH * OD + 64 + lane];                // junk if !hi
        float acc0 = 0.f, acc1 = 0.f;

#define CGROUP(iv, base)                                                   \
        {                                                                  \
            const float* t0 = ws + (iv).x * OD;                            \
            const float* t1 = ws + (iv).y * OD;                            \
            const float* t2 = ws + (iv).z * OD;                            \
            const float* t3 = ws + (iv).w * OD;                            \
            float v0 = t0[lane], w0 = t0[64 + lane];                       \
            float v1 = t1[lane], w1 = t1[64 + lane];                       \
            float v2 = t2[lane], w2 = t2[64 + lane];                       \
            float v3 = t3[lane], w3 = t3[64 + lane];                       \
            acc0 += ((base) + 0 < len) ? v0 : 0.f;                         \
            acc1 += ((base) + 0 < len) ? w0 : 0.f;                         \
            acc0 += ((base) + 1 < len) ? v1 : 0.f;                         \
            acc1 += ((base) + 1 < len) ? w1 : 0.f;                         \
            acc0 += ((base) + 2 < len) ? v2 : 0.f;                         \
            acc1 += ((base) + 2 < len) ? w2 : 0.f;                         \
            acc0 += ((base) + 3 < len) ? v3 : 0.f;                         \
            acc1 += ((base) + 3 < len) ? w3 : 0.f;                         \
        }

        CGROUP(i0, 0)                       // len >= 1 always
        if (len > 4)  CGROUP(i1, 4)
        if (len > 8)  CGROUP(i2, 8)
        if (len > 12) CGROUP(i3, 12)
#undef CGROUP

        const float inv = 1.f / (float)len;
        float* co = out + (size_t)word * (GD + OD) + GD;
        co[lane] = fmaf(acc0, inv, cl);
        if (hi) co[64 + lane] = fmaf(acc1, inv, chv);
    }
}

// ---------------- fallback: proven R11 two-kernel path ----------------
__global__ __launch_bounds__(256) void k_pre_glove(
        const int*   __restrict__ word_tokens,
        const float* __restrict__ glove,
        const float* __restrict__ char_table,
        const float* __restrict__ conv_w,
        const float* __restrict__ conv_b,
        const float* __restrict__ lin_w,
        const float* __restrict__ lin_b,
        float* __restrict__ ws,
        float* __restrict__ out) {
    if (blockIdx.x < NCH) {
        __shared__ float ceS[CEM];
        __shared__ float U[OD];
        const int t  = threadIdx.x;
        const int ch = blockIdx.x;

        if (t < CEM) ceS[t] = char_table[ch * CEM + t];
        __syncthreads();

        if (t < OD) {
            const float* cw = conv_w + t * CEM;
            float a0 = 0.f, a1 = 0.f, a2 = 0.f, a3 = 0.f;
            #pragma unroll
            for (int e = 0; e < CEM; e += 4) {
                a0 = fmaf(cw[e + 0], ceS[e + 0], a0);
                a1 = fmaf(cw[e + 1], ceS[e + 1], a1);
                a2 = fmaf(cw[e + 2], ceS[e + 2], a2);
                a3 = fmaf(cw[e + 3], ceS[e + 3], a3);
            }
            U[t] = (a0 + a1) + (a2 + a3);
        }
        __syncthreads();

        if (t < OD) {
            const float* lw = lin_w + t * OD;
            float a0 = 0.f, a1 = 0.f, a2 = 0.f, a3 = 0.f;
            #pragma unroll 5
            for (int j = 0; j < OD; j += 4) {
                a0 = fmaf(lw[j + 0], U[j + 0], a0);
                a1 = fmaf(lw[j + 1], U[j + 1], a1);
                a2 = fmaf(lw[j + 2], U[j + 2], a2);
                a3 = fmaf(lw[j + 3], U[j + 3], a3);
            }
            ws[ch * OD + t] = (a0 + a1) + (a2 + a3);

            if (ch == 0) {
                float b0 = lin_b[t], b1 = 0.f, b2 = 0.f, b3 = 0.f;
                #pragma unroll 5
                for (int j = 0; j < OD; j += 4) {
                    b0 = fmaf(lw[j + 0], conv_b[j + 0], b0);
                    b1 = fmaf(lw[j + 1], conv_b[j + 1], b1);
                    b2 = fmaf(lw[j + 2], conv_b[j + 2], b2);
                    b3 = fmaf(lw[j + 3], conv_b[j + 3], b3);
                }
                ws[NCH * OD + t] = (b0 + b1) + (b2 + b3);
            }
        }
    } else {
        const int wave = threadIdx.x >> 6;
        const int lane = threadIdx.x & 63;
        const int word = (blockIdx.x - NCH) * 4 + wave;

        const int tok = word_tokens[word];
        const float4* g4 = (const float4*)(glove + (size_t)tok * GD);
        float4 g0 = g4[lane];
        float4 g1;
        const bool tail = lane < (GD / 4 - 64);
        if (tail) g1 = g4[64 + lane];

        float4* d4 = (float4*)(out + (size_t)word * (GD + OD));
        d4[lane] = g0;
        if (tail) d4[64 + lane] = g1;
    }
}

__global__ __launch_bounds__(256) void k_char(
        const int*   __restrict__ char_ids,
        const int*   __restrict__ char_lens,
        const float* __restrict__ ws,
        float*       __restrict__ out) {
    const int wave = threadIdx.x >> 6;
    const int lane = threadIdx.x & 63;
    const int word = blockIdx.x * 4 + wave;

    const int len = char_lens[word];

    const int4* cid4 = (const int4*)(char_ids + (size_t)word * LW);
    const int4 i0 = cid4[0], i1 = cid4[1], i2 = cid4[2], i3 = cid4[3];

    const float cl = ws[NCH * OD + lane];
    const bool hi = lane < (OD - 64);
    const float chv = ws[NCH * OD + 64 + lane];
    float acc0 = 0.f, acc1 = 0.f;

#define CGROUP(iv, base)                                                   \
    {                                                                      \
        const float* t0 = ws + (iv).x * OD;                                \
        const float* t1 = ws + (iv).y * OD;                                \
        const float* t2 = ws + (iv).z * OD;                                \
        const float* t3 = ws + (iv).w * OD;                                \
        float v0 = t0[lane], w0 = t0[64 + lane];                           \
        float v1 = t1[lane], w1 = t1[64 + lane];                           \
        float v2 = t2[lane], w2 = t2[64 + lane];                           \
        float v3 = t3[lane], w3 = t3[64 + lane];                           \
        acc0 += ((base) + 0 < len) ? v0 : 0.f;                             \
        acc1 += ((base) + 0 < len) ? w0 : 0.f;                             \
        acc0 += ((base) + 1 < len) ? v1 : 0.f;                             \
        acc1 += ((base) + 1 < len) ? w1 : 0.f;                             \
        acc0 += ((base) + 2 < len) ? v2 : 0.f;                             \
        acc1 += ((base) + 2 < len) ? w2 : 0.f;                             \
        acc0 += ((base) + 3 < len) ? v3 : 0.f;                             \
        acc1 += ((base) + 3 < len) ? w3 : 0.f;                             \
    }

    CGROUP(i0, 0)
    if (len > 4)  CGROUP(i1, 4)
    if (len > 8)  CGROUP(i2, 8)
    if (len > 12) CGROUP(i3, 12)
#undef CGROUP

    const float inv = 1.f / (float)len;
    float* co = out + (size_t)word * (GD + OD) + GD;
    co[lane] = fmaf(acc0, inv, cl);
    if (hi) co[64 + lane] = fmaf(acc1, inv, chv);
}

extern "C" void kernel_launch(void* const* d_in, const int* in_sizes, int n_in,
                              void* d_out, int out_size, void* d_ws, size_t ws_size,
                              hipStream_t stream) {
    const int*   word_tokens = (const int*)  d_in[0];
    const int*   char_ids    = (const int*)  d_in[1];
    const int*   char_lens   = (const int*)  d_in[2];
    const float* glove       = (const float*)d_in[3];
    const float* char_table  = (const float*)d_in[4];
    const float* conv_w      = (const float*)d_in[5];
    const float* conv_b      = (const float*)d_in[6];
    const float* lin_w       = (const float*)d_in[7];
    const float* lin_b       = (const float*)d_in[8];
    float* out = (float*)d_out;
    float* ws  = (float*)d_ws;   // needs 12928 floats ~= 51.7 KB

    void* args[] = {(void*)&word_tokens, (void*)&char_ids, (void*)&char_lens,
                    (void*)&glove, (void*)&char_table, (void*)&conv_w,
                    (void*)&conv_b, (void*)&lin_w, (void*)&lin_b,
                    (void*)&ws, (void*)&out};
    hipError_t err = hipLaunchCooperativeKernel(
        (const void*)mono, dim3(GRID), dim3(256), args, 0, stream);

    if (err != hipSuccess) {
        // deterministic fallback: proven R11 two-kernel path (same math)
        k_pre_glove<<<NCH + NW / 4, 256, 0, stream>>>(
            word_tokens, glove, char_table, conv_w, conv_b, lin_w, lin_b, ws, out);
        k_char<<<NW / 4, 256, 0, stream>>>(char_ids, char_lens, ws, out);
    }
}

// Round 14
// 21.856 us; speedup vs baseline: 7.3106x; 7.3106x over previous
//
#include <hip/hip_runtime.h>

// Problem dims (fixed by the reference)
#define LW   16      // chars per word (max)
#define GD   300     // glove dim
#define CEM  64      // char emb dim
#define OD   100     // out dim of conv/linear
#define NCH  128     // char vocab
#define NW   (32 * 512)   // 16384 words

// d_ws layout:
//   ushort T16[12800]  bytes [0 .. 25600)            = floats [0 .. 6400)
//   pad    ushorts 12800..13055 (junk-lane T reads)  = floats [6400 .. 6528)
//   float  c[100]      floats [6528 .. 6628)
//   pad    floats 6628..6656 (junk-lane bias reads touch up to 6655)
// needs 6656 floats = 26.6 KB of d_ws.
#define COFF 6528    // float offset of c[]

__device__ __forceinline__ unsigned short f2bf(float x) {
    unsigned int u = __float_as_uint(x);
    return (unsigned short)((u + 0x7FFFu + ((u >> 16) & 1u)) >> 16);   // RN
}
__device__ __forceinline__ float bf2f(unsigned short h) {
    return __uint_as_float((unsigned int)h << 16);
}

// K1: blocks 0..127 run the precompute body (ch = blockIdx), storing T in bf16;
// blocks 128.. copy glove rows for 4 words each (wave = word). The precompute's
// latency-bound work hides under the glove streaming on the other blocks.
__global__ __launch_bounds__(256) void k_pre_glove(
        const int*   __restrict__ word_tokens,
        const float* __restrict__ glove,
        const float* __restrict__ char_table,
        const float* __restrict__ conv_w,
        const float* __restrict__ conv_b,
        const float* __restrict__ lin_w,
        const float* __restrict__ lin_b,
        float* __restrict__ ws,
        float* __restrict__ out) {
    if (blockIdx.x < NCH) {
        // ---- precompute_T body (R5 math; threads 128..255 idle) ----
        __shared__ float ceS[CEM];
        __shared__ float U[OD];
        const int t  = threadIdx.x;
        const int ch = blockIdx.x;

        if (t < CEM) ceS[t] = char_table[ch * CEM + t];
        __syncthreads();

        if (t < OD) {
            const float* cw = conv_w + t * CEM;
            float a0 = 0.f, a1 = 0.f, a2 = 0.f, a3 = 0.f;
            #pragma unroll
            for (int e = 0; e < CEM; e += 4) {
                a0 = fmaf(cw[e + 0], ceS[e + 0], a0);
                a1 = fmaf(cw[e + 1], ceS[e + 1], a1);
                a2 = fmaf(cw[e + 2], ceS[e + 2], a2);
                a3 = fmaf(cw[e + 3], ceS[e + 3], a3);
            }
            U[t] = (a0 + a1) + (a2 + a3);
        }
        __syncthreads();

        if (t < OD) {
            const float* lw = lin_w + t * OD;
            float a0 = 0.f, a1 = 0.f, a2 = 0.f, a3 = 0.f;
            #pragma unroll 5
            for (int j = 0; j < OD; j += 4) {
                a0 = fmaf(lw[j + 0], U[j + 0], a0);
                a1 = fmaf(lw[j + 1], U[j + 1], a1);
                a2 = fmaf(lw[j + 2], U[j + 2], a2);
                a3 = fmaf(lw[j + 3], U[j + 3], a3);
            }
            ((unsigned short*)ws)[ch * OD + t] = f2bf((a0 + a1) + (a2 + a3));

            if (ch == 0) {
                float b0 = lin_b[t], b1 = 0.f, b2 = 0.f, b3 = 0.f;
                #pragma unroll 5
                for (int j = 0; j < OD; j += 4) {
                    b0 = fmaf(lw[j + 0], conv_b[j + 0], b0);
                    b1 = fmaf(lw[j + 1], conv_b[j + 1], b1);
                    b2 = fmaf(lw[j + 2], conv_b[j + 2], b2);
                    b3 = fmaf(lw[j + 3], conv_b[j + 3], b3);
                }
                ws[COFF + t] = (b0 + b1) + (b2 + b3);   // bias stays f32
            }
        }
    } else {
        // ---- glove copy: wave = word, 75 float4 per word ----
        const int wave = threadIdx.x >> 6;
        const int lane = threadIdx.x & 63;
        const int word = (blockIdx.x - NCH) * 4 + wave;

        const int tok = word_tokens[word];              // wave-uniform
        const float4* g4 = (const float4*)(glove + (size_t)tok * GD);
        float4 g0 = g4[lane];
        float4 g1;
        const bool tail = lane < (GD / 4 - 64);         // lanes 0..10
        if (tail) g1 = g4[64 + lane];

        float4* d4 = (float4*)(out + (size_t)word * (GD + OD));
        d4[lane] = g0;
        if (tail) d4[64 + lane] = g1;
    }
}

// K2: char path per wave. Same shape as R11's k_char, but T rows are bf16
// (25.6 KB -> L1-resident, half the gather bytes). Converts via shift.
__global__ __launch_bounds__(256) void k_char(
        const int*   __restrict__ char_ids,
        const int*   __restrict__ char_lens,
        const float* __restrict__ ws,
        float*       __restrict__ out) {
    const int wave = threadIdx.x >> 6;
    const int lane = threadIdx.x & 63;
    const int word = blockIdx.x * 4 + wave;

    const int len = char_lens[word];                // wave-uniform, >= 1

    const int4* cid4 = (const int4*)(char_ids + (size_t)word * LW);
    const int4 i0 = cid4[0], i1 = cid4[1], i2 = cid4[2], i3 = cid4[3];

    const unsigned short* T16 = (const unsigned short*)ws;

    // bias (load early, hides under gather); junk lanes read pad, masked later
    const float cl = ws[COFF + lane];                              // c[lane]
    const bool hi = lane < (OD - 64);                              // lanes 0..35
    const float chv = ws[COFF + 64 + lane];
    float acc0 = 0.f, acc1 = 0.f;

    // T rows: 64 ushorts (128B line) per half; junk reads max 12827 < 13056 pad.
#define CGROUP(iv, base)                                                   \
    {                                                                      \
        const unsigned short* t0 = T16 + (iv).x * OD;                      \
        const unsigned short* t1 = T16 + (iv).y * OD;                      \
        const unsigned short* t2 = T16 + (iv).z * OD;                      \
        const unsigned short* t3 = T16 + (iv).w * OD;                      \
        float v0 = bf2f(t0[lane]), w0 = bf2f(t0[64 + lane]);               \
        float v1 = bf2f(t1[lane]), w1 = bf2f(t1[64 + lane]);               \
        float v2 = bf2f(t2[lane]), w2 = bf2f(t2[64 + lane]);               \
        float v3 = bf2f(t3[lane]), w3 = bf2f(t3[64 + lane]);               \
        acc0 += ((base) + 0 < len) ? v0 : 0.f;                             \
        acc1 += ((base) + 0 < len) ? w0 : 0.f;                             \
        acc0 += ((base) + 1 < len) ? v1 : 0.f;                             \
        acc1 += ((base) + 1 < len) ? w1 : 0.f;                             \
        acc0 += ((base) + 2 < len) ? v2 : 0.f;                             \
        acc1 += ((base) + 2 < len) ? w2 : 0.f;                             \
        acc0 += ((base) + 3 < len) ? v3 : 0.f;                             \
        acc1 += ((base) + 3 < len) ? w3 : 0.f;                             \
    }

    CGROUP(i0, 0)                       // len >= 1 always
    if (len > 4)  CGROUP(i1, 4)
    if (len > 8)  CGROUP(i2, 8)
    if (len > 12) CGROUP(i3, 12)
#undef CGROUP

    const float inv = 1.f / (float)len;
    float* co = out + (size_t)word * (GD + OD) + GD;
    co[lane] = fmaf(acc0, inv, cl);
    if (hi) co[64 + lane] = fmaf(acc1, inv, chv);
}

extern "C" void kernel_launch(void* const* d_in, const int* in_sizes, int n_in,
                              void* d_out, int out_size, void* d_ws, size_t ws_size,
                              hipStream_t stream) {
    const int*   word_tokens = (const int*)  d_in[0];
    const int*   char_ids    = (const int*)  d_in[1];
    const int*   char_lens   = (const int*)  d_in[2];
    const float* glove       = (const float*)d_in[3];
    const float* char_table  = (const float*)d_in[4];
    const float* conv_w      = (const float*)d_in[5];
    const float* conv_b      = (const float*)d_in[6];
    const float* lin_w       = (const float*)d_in[7];
    const float* lin_b       = (const float*)d_in[8];
    float* out = (float*)d_out;
    float* ws  = (float*)d_ws;   // needs 6656 floats ~= 26.6 KB

    k_pre_glove<<<NCH + NW / 4, 256, 0, stream>>>(
        word_tokens, glove, char_table, conv_w, conv_b, lin_w, lin_b, ws, out);

    k_char<<<NW / 4, 256, 0, stream>>>(char_ids, char_lens, ws, out);
}